// Round 8
// baseline (122.055 us; speedup 1.0000x reference)
//
#include <hip/hip_runtime.h>
#include <hip/hip_bf16.h>

typedef unsigned int uint;
typedef unsigned short ushort;
typedef short bf16x8 __attribute__((ext_vector_type(8)));
typedef ushort u16x8 __attribute__((ext_vector_type(8)));
typedef float f32x4 __attribute__((ext_vector_type(4)));

#define B_ 16
#define C_ 256
#define O_ 256
#define HW_ 4096
#define KK_ 2304   // 9 * 256, tap-major: k = tap*256 + c
#define HP_ 66     // halo-padded spatial dim

#define VMW(n) asm volatile("s_waitcnt vmcnt(" #n ")" ::: "memory")
#define LGW(n) asm volatile("s_waitcnt lgkmcnt(" #n ")" ::: "memory")

__device__ __forceinline__ ushort f2bf(float f) {
    uint u = __builtin_bit_cast(uint, f);
    uint r = (u + 0x7FFFu + ((u >> 16) & 1u)) >> 16;   // RNE
    return (ushort)r;
}

// async global->LDS, 16B per lane; LDS dest is wave-uniform base + lane*16
__device__ __forceinline__ void gl16(const ushort* g, ushort* l) {
    __builtin_amdgcn_global_load_lds(
        (const __attribute__((address_space(1))) void*)g,
        (__attribute__((address_space(3))) void*)l,
        16, 0, 0);
}

// ---------------- kernel 1: NCHW f32 -> padded NHWC bf16 + pool partials + halo ------
__global__ __launch_bounds__(256) void transpose_kernel(const float* __restrict__ x,
                                                        ushort* __restrict__ xT,
                                                        float* __restrict__ part) {
    __shared__ ushort tl[64][264];   // [w][c], pad 8 -> row stride 528B
    const int h = blockIdx.x, b = blockIdx.y;
    const int c = threadIdx.x;
    const float* src = x + (((size_t)(b * C_ + c)) * 64 + h) * 64;   // x[b][c][h][*]
    float s = 0.0f;
    #pragma unroll
    for (int j = 0; j < 16; ++j) {
        float4 v = ((const float4*)src)[j];
        s += v.x + v.y + v.z + v.w;
        tl[j * 4 + 0][c] = f2bf(v.x);
        tl[j * 4 + 1][c] = f2bf(v.y);
        tl[j * 4 + 2][c] = f2bf(v.z);
        tl[j * 4 + 3][c] = f2bf(v.w);
    }
    part[(b * C_ + c) * 64 + h] = s;
    // zero 5 halo pixels per block (260 total per sample, 64 blocks x 5 = 320 >= 260)
    ushort* xbs = xT + (size_t)b * HP_ * HP_ * C_;
    #pragma unroll
    for (int t = 0; t < 5; ++t) {
        int i = h * 5 + t;
        if (i < 260) {
            int hp, wp;
            if (i < 66)       { hp = 0;       wp = i;       }
            else if (i < 132) { hp = 65;      wp = i - 66;  }
            else if (i < 196) { hp = i - 131; wp = 0;       }
            else              { hp = i - 195; wp = 65;      }
            xbs[((size_t)hp * HP_ + wp) * C_ + c] = 0;
        }
    }
    __syncthreads();
    const int cw = threadIdx.x & 31, rw = threadIdx.x >> 5;
    ushort* dstrow = xT + (((size_t)(b * HP_) + h + 1) * HP_ + 1) * C_;  // xT[b][h+1][1][0]
    #pragma unroll
    for (int j = 0; j < 8; ++j) {
        int w = rw + 8 * j;
        *(u16x8*)(dstrow + (size_t)w * C_ + cw * 8) = *(const u16x8*)&tl[w][cw * 8];
    }
}

// ---------------- kernel 2: pooled reduce + gating softmax ----------------
__global__ __launch_bounds__(256) void gate_kernel(const float* __restrict__ part,
                                                   const float* __restrict__ gw,
                                                   float* __restrict__ gates) {
    const int b = blockIdx.x, c = threadIdx.x;
    const float4* pp = (const float4*)(part + (size_t)(b * C_ + c) * 64);
    float p = 0.0f;
    #pragma unroll
    for (int j = 0; j < 16; ++j) { float4 v = pp[j]; p += v.x + v.y + v.z + v.w; }
    p *= (1.0f / 4096.0f);
    float l0 = p * gw[0 * C_ + c], l1 = p * gw[1 * C_ + c];
    float l2 = p * gw[2 * C_ + c], l3 = p * gw[3 * C_ + c];
    #pragma unroll
    for (int off = 32; off; off >>= 1) {
        l0 += __shfl_down(l0, off); l1 += __shfl_down(l1, off);
        l2 += __shfl_down(l2, off); l3 += __shfl_down(l3, off);
    }
    __shared__ float red[4][4];
    const int wid = c >> 6, lane = c & 63;
    if (lane == 0) { red[wid][0] = l0; red[wid][1] = l1; red[wid][2] = l2; red[wid][3] = l3; }
    __syncthreads();
    if (c < 4) {
        float logit = red[0][c] + red[1][c] + red[2][c] + red[3][c];
        float m = logit;
        m = fmaxf(m, __shfl_xor(m, 1)); m = fmaxf(m, __shfl_xor(m, 2));
        float ex = expf(logit - m);
        float ssum = ex; ssum += __shfl_xor(ssum, 1); ssum += __shfl_xor(ssum, 2);
        gates[b * 4 + c] = ex / ssum;
    }
}

// ---------------- kernel 3: combine expert weights (tap-major k) ----------------
__global__ __launch_bounds__(256) void combine_kernel(const float* __restrict__ We,
                                                      const float* __restrict__ gates,
                                                      ushort* __restrict__ Wc) {
    const int o = blockIdx.x, c = threadIdx.x;
    __shared__ float g[64];
    if (c < 64) g[c] = gates[c];
    __syncthreads();
    float w[4][9];
    #pragma unroll
    for (int e = 0; e < 4; ++e) {
        const float* p = We + (((size_t)e * O_ + o) * C_ + c) * 9;
        #pragma unroll
        for (int tap = 0; tap < 9; ++tap) w[e][tap] = p[tap];
    }
    #pragma unroll
    for (int b = 0; b < B_; ++b) {
        float g0 = g[b*4+0], g1 = g[b*4+1], g2 = g[b*4+2], g3 = g[b*4+3];
        #pragma unroll
        for (int tap = 0; tap < 9; ++tap) {
            float v = g0*w[0][tap] + g1*w[1][tap] + g2*w[2][tap] + g3*w[3][tap];
            Wc[((size_t)(b * O_ + o)) * KK_ + tap * C_ + c] = f2bf(v);
        }
    }
}

// ---------------- kernel 4: 256x256 conv GEMM, BK=32, 4-slot ring, counted vmcnt ----
// grid = 256 blocks (16 n-tiles x 16 samples) = 1/CU, 512 threads (8 waves, 2M x 4N).
// 72 K-tiles of BK=32 (tap-uniform). 4-slot LDS ring (128KB), depth-2 DMA prefetch:
// tile t computes slot t&3 while t+2, t+3 stream in; per tile ONE barrier and ONE
// COUNTED vmcnt(8) (never 0 mid-loop, T4). Frag reads pipelined one phase ahead.
// Both-sides XOR granule swizzle (g ^= row&3) -> conflict-free b128 reads.
__global__ __launch_bounds__(512, 2) void conv_kernel(const ushort* __restrict__ xT,
                                                      const ushort* __restrict__ Wc,
                                                      float* __restrict__ out) {
    __shared__ ushort As[4][256][32];   // [slot][o][k]   64B rows, linear DMA dest
    __shared__ ushort Bs[4][256][32];   // [slot][px][k]

    // bijective XCD chunk swizzle: 32 consecutive wgids per XCD (2 samples/XCD)
    const int d = blockIdx.x;
    const int wgid = (d & 7) * 32 + (d >> 3);
    const int b  = wgid >> 4;
    const int n0 = (wgid & 15) * 256;

    const int tid = threadIdx.x;
    const int wid = tid >> 6, lane = tid & 63;
    const int lr = lane & 15, lg = lane >> 4;
    const int wro = (wid >> 2) * 128;           // wave M-offset (o)
    const int wco = (wid & 3) * 64;             // wave N-offset (px)

    // staging roles: wave stages rows [32*wid, 32*wid+32) of A and B (2 gl16 each)
    const int srow = lane >> 2;                 // 0..15 row within 16-row chunk
    const int sgr  = (lane & 3) ^ (srow & 3);   // source granule (XOR swizzle)
    const ushort* aS = Wc + ((size_t)(b * O_ + wid * 32 + srow)) * KK_ + sgr * 8;
    const ushort* xb = xT + (size_t)b * HP_ * HP_ * C_;
    const int p0 = n0 + wid * 32 + srow;
    const int p1 = p0 + 16;
    const ushort* bS0 = xb + ((size_t)(((p0 >> 6) + 1) * HP_ + (p0 & 63) + 1)) * C_ + sgr * 8;
    const ushort* bS1 = xb + ((size_t)(((p1 >> 6) + 1) * HP_ + (p1 & 63) + 1)) * C_ + sgr * 8;

    f32x4 acc[8][4];
    #pragma unroll
    for (int i = 0; i < 8; ++i)
        #pragma unroll
        for (int j = 0; j < 4; ++j) acc[i][j] = (f32x4){0.f, 0.f, 0.f, 0.f};

    auto stage = [&](int ss, int t) {
        const int tap = t >> 3, c0 = (t & 7) * 32;
        const int t3 = (tap * 11) >> 5;          // tap/3
        const int toff = ((t3 - 1) * HP_ + (tap - 3 * t3 - 1)) * C_ + c0;
        gl16(aS + t * 32,                  &As[ss][wid * 32][0]);
        gl16(aS + t * 32 + (size_t)16 * KK_, &As[ss][wid * 32 + 16][0]);
        gl16(bS0 + toff,                   &Bs[ss][wid * 32][0]);
        gl16(bS1 + toff,                   &Bs[ss][wid * 32 + 16][0]);
    };

    bf16x8 aLo[4], aHi[4], bF[4];

    auto dsA = [&](int s, int half, bf16x8* dst) {
        #pragma unroll
        for (int m = 0; m < 4; ++m)
            dst[m] = *(const bf16x8*)
                &As[s][wro + half * 64 + m * 16 + lr][(lg ^ (lr & 3)) * 8];
    };
    auto dsB = [&](int s, bf16x8* dst) {
        #pragma unroll
        for (int n = 0; n < 4; ++n)
            dst[n] = *(const bf16x8*)
                &Bs[s][wco + n * 16 + lr][(lg ^ (lr & 3)) * 8];
    };
    auto mfma16 = [&](int ao, bf16x8* a, bf16x8* bv) {
        #pragma unroll
        for (int m = 0; m < 4; ++m)
            #pragma unroll
            for (int n = 0; n < 4; ++n)
                acc[ao + m][n] = __builtin_amdgcn_mfma_f32_16x16x32_bf16(a[m], bv[n], acc[ao + m][n], 0, 0, 0);
    };

    // prologue: stage tiles 0..2; wait tile 0 (1,2 stay in flight); pre-batch tile 0
    stage(0, 0); stage(1, 1); stage(2, 2);
    VMW(8);
    __builtin_amdgcn_s_barrier();
    dsB(0, bF); dsA(0, 0, aLo);

    #pragma unroll 1
    for (int t = 0; t < 68; ++t) {
        const int s = t & 3, sn = (t + 1) & 3;
        stage((t + 3) & 3, t + 3);
        dsA(s, 1, aHi);
        LGW(4);                                   // pre-batch (aLo,bF) ready
        __builtin_amdgcn_sched_barrier(0);
        __builtin_amdgcn_s_setprio(1);
        mfma16(0, aLo, bF);
        __builtin_amdgcn_s_setprio(0);
        LGW(0);                                   // aHi ready
        __builtin_amdgcn_sched_barrier(0);
        __builtin_amdgcn_s_setprio(1);
        mfma16(4, aHi, bF);
        __builtin_amdgcn_s_setprio(0);
        VMW(8);                                   // tile t+1 landed; t+2,t+3 in flight
        __builtin_amdgcn_s_barrier();
        dsB(sn, bF); dsA(sn, 0, aLo);             // pre-batch next tile
    }
    // t=68 (s=0): stage tile 71, then vmcnt(8)
    {
        stage(3, 71);
        dsA(0, 1, aHi);
        LGW(4); __builtin_amdgcn_sched_barrier(0);
        __builtin_amdgcn_s_setprio(1); mfma16(0, aLo, bF); __builtin_amdgcn_s_setprio(0);
        LGW(0); __builtin_amdgcn_sched_barrier(0);
        __builtin_amdgcn_s_setprio(1); mfma16(4, aHi, bF); __builtin_amdgcn_s_setprio(0);
        VMW(8);
        __builtin_amdgcn_s_barrier();
        dsB(1, bF); dsA(1, 0, aLo);
    }
    // t=69 (s=1): no stage; vmcnt(4) (tile 71 in flight)
    {
        dsA(1, 1, aHi);
        LGW(4); __builtin_amdgcn_sched_barrier(0);
        __builtin_amdgcn_s_setprio(1); mfma16(0, aLo, bF); __builtin_amdgcn_s_setprio(0);
        LGW(0); __builtin_amdgcn_sched_barrier(0);
        __builtin_amdgcn_s_setprio(1); mfma16(4, aHi, bF); __builtin_amdgcn_s_setprio(0);
        VMW(4);
        __builtin_amdgcn_s_barrier();
        dsB(2, bF); dsA(2, 0, aLo);
    }
    // t=70 (s=2): no stage; final drain vmcnt(0)
    {
        dsA(2, 1, aHi);
        LGW(4); __builtin_amdgcn_sched_barrier(0);
        __builtin_amdgcn_s_setprio(1); mfma16(0, aLo, bF); __builtin_amdgcn_s_setprio(0);
        LGW(0); __builtin_amdgcn_sched_barrier(0);
        __builtin_amdgcn_s_setprio(1); mfma16(4, aHi, bF); __builtin_amdgcn_s_setprio(0);
        VMW(0);
        __builtin_amdgcn_s_barrier();
        dsB(3, bF); dsA(3, 0, aLo);
    }
    // t=71 (s=3)
    {
        dsA(3, 1, aHi);
        LGW(4); __builtin_amdgcn_sched_barrier(0);
        mfma16(0, aLo, bF);
        LGW(0); __builtin_amdgcn_sched_barrier(0);
        mfma16(4, aHi, bF);
    }

    // epilogue: C/D layout col=lane&15, row=(lane>>4)*4+j
    #pragma unroll
    for (int m = 0; m < 8; ++m)
        #pragma unroll
        for (int n = 0; n < 4; ++n)
            #pragma unroll
            for (int j = 0; j < 4; ++j) {
                int ro = wro + m * 16 + lg * 4 + j;
                int co = n0 + wco + n * 16 + lr;
                out[((size_t)(b * O_ + ro)) * HW_ + co] = acc[m][n][j];
            }
}

extern "C" void kernel_launch(void* const* d_in, const int* in_sizes, int n_in,
                              void* d_out, int out_size, void* d_ws, size_t ws_size,
                              hipStream_t stream) {
    const float* x  = (const float*)d_in[0];
    const float* We = (const float*)d_in[1];
    const float* gw = (const float*)d_in[2];
    float* out = (float*)d_out;

    // ws: part @0 (256KB), gates @262144, Wc @263168 (18.87MB -> 19137536),
    //     xT @19137536 (16*66*66*256*2B = 35.68MB) -> ~54.8MB total
    float*  part  = (float*)d_ws;
    float*  gates = (float*)((char*)d_ws + 262144);
    ushort* Wcomb = (ushort*)((char*)d_ws + 263168);
    ushort* xTp   = (ushort*)((char*)d_ws + 19137536);

    transpose_kernel<<<dim3(64, 16), 256, 0, stream>>>(x, xTp, part);
    gate_kernel<<<16, 256, 0, stream>>>(part, gw, gates);
    combine_kernel<<<O_, 256, 0, stream>>>(We, gates, Wcomb);
    conv_kernel<<<256, 512, 0, stream>>>(xTp, Wcomb, out);
}